// Round 11
// baseline (826.754 us; speedup 1.0000x reference)
//
#include <hip/hip_runtime.h>

typedef unsigned short u16;
typedef unsigned long long u64;
typedef __attribute__((ext_vector_type(8))) short bf16x8;
typedef __attribute__((ext_vector_type(4))) float f32x4;

#define MFMA16(a, b, c) __builtin_amdgcn_mfma_f32_16x16x32_bf16((a), (b), (c), 0, 0, 0)

// ---- problem sizes ----
#define TT 128
#define BB 128
#define IN_ 512
#define HH 512
#define G4 2048   // 4*H
#define OUTD 512
#define TB 16384  // T*B

#define AEXLD(p) __hip_atomic_load((p), __ATOMIC_RELAXED, __HIP_MEMORY_SCOPE_AGENT)

__device__ __forceinline__ u16 f2bf(float f) {
    union { float f; unsigned u; } v; v.f = f;
    unsigned r = v.u + 0x7FFFu + ((v.u >> 16) & 1u);
    return (u16)(r >> 16);
}
__device__ __forceinline__ float bf2f(u16 h) {
    union { unsigned u; float f; } v; v.u = ((unsigned)h) << 16; return v.f;
}
__device__ __forceinline__ float sigmoid_f(float x) { return 1.f / (1.f + __expf(-x)); }
__device__ __forceinline__ float tanh_f(float x) {
    float e = __expf(2.f * x);
    return 1.f - 2.f / (e + 1.f);
}

// ---- async global->LDS, 16B per lane (LDS dest = wave-uniform base + lane*16) ----
typedef unsigned __attribute__((address_space(1))) guint;
typedef unsigned __attribute__((address_space(3))) luint;
__device__ __forceinline__ void gll16(const u16* g, u16* l) {
    __builtin_amdgcn_global_load_lds((guint*)(void*)g, (luint*)(void*)l, 16, 0, 0);
}

#define TMASK 0xFFFF0000FFFF0000ull
__device__ __forceinline__ bool tag_ok(const u64 v[16], u64 expect) {
    bool ok = true;
    #pragma unroll
    for (int i = 0; i < 16; ++i)
        ok &= ((v[i] & TMASK) == expect);
    return ok;
}
// slow/correctness volley: 16 coalesced UC (agent-scope) loads, L3-served.
__device__ __forceinline__ void slow_volley16(const u64* b, u64 v[16]) {
    #pragma unroll
    for (int i = 0; i < 16; ++i)
        v[i] = AEXLD(b + (size_t)i * 256);
}
// fast volley: 16 coalesced sc0 loads (L1-bypass, L2-served). Rows 2048B apart:
// 8 base addrs x {0,2048} imm offsets. Early-clobber outputs; single waitcnt.
__device__ __forceinline__ void fast_volley16(const u64* b, u64 v[16]) {
    asm volatile(
        "global_load_dwordx2 %0, %16, off sc0\n\t"
        "global_load_dwordx2 %1, %16, off offset:2048 sc0\n\t"
        "global_load_dwordx2 %2, %17, off sc0\n\t"
        "global_load_dwordx2 %3, %17, off offset:2048 sc0\n\t"
        "global_load_dwordx2 %4, %18, off sc0\n\t"
        "global_load_dwordx2 %5, %18, off offset:2048 sc0\n\t"
        "global_load_dwordx2 %6, %19, off sc0\n\t"
        "global_load_dwordx2 %7, %19, off offset:2048 sc0\n\t"
        "global_load_dwordx2 %8, %20, off sc0\n\t"
        "global_load_dwordx2 %9, %20, off offset:2048 sc0\n\t"
        "global_load_dwordx2 %10, %21, off sc0\n\t"
        "global_load_dwordx2 %11, %21, off offset:2048 sc0\n\t"
        "global_load_dwordx2 %12, %22, off sc0\n\t"
        "global_load_dwordx2 %13, %22, off offset:2048 sc0\n\t"
        "global_load_dwordx2 %14, %23, off sc0\n\t"
        "global_load_dwordx2 %15, %23, off offset:2048 sc0\n\t"
        "s_waitcnt vmcnt(0)"
        : "=&v"(v[0]), "=&v"(v[1]), "=&v"(v[2]), "=&v"(v[3]),
          "=&v"(v[4]), "=&v"(v[5]), "=&v"(v[6]), "=&v"(v[7]),
          "=&v"(v[8]), "=&v"(v[9]), "=&v"(v[10]), "=&v"(v[11]),
          "=&v"(v[12]), "=&v"(v[13]), "=&v"(v[14]), "=&v"(v[15])
        : "v"(b), "v"(b + 512), "v"(b + 1024), "v"(b + 1536),
          "v"(b + 2048), "v"(b + 2560), "v"(b + 3072), "v"(b + 3584)
        : "memory");
}

// ---- fused prep: all bf16 converts + stacked bias + BOTH exchange buffers zero ----
__global__ void prep_kernel(
    const float* __restrict__ x,
    const float* __restrict__ Wihf, const float* __restrict__ Wihb,
    const float* __restrict__ Whhf, const float* __restrict__ Whhb,
    const float* __restrict__ Wlin,
    const float* __restrict__ bihf, const float* __restrict__ bhhf,
    const float* __restrict__ bihb, const float* __restrict__ bhhb,
    u16* __restrict__ x_bf, u16* __restrict__ wih_cat,
    u16* __restrict__ whhf_bf, u16* __restrict__ whhb_bf,
    u16* __restrict__ wlin_bf, float* __restrict__ bias_cat,
    uint4* __restrict__ exch) {
    const int i0 = blockIdx.x * blockDim.x + threadIdx.x;
    const int stride = gridDim.x * blockDim.x;
    #define CVT4(SRC, DST, N4, DOFF)                                        \
        for (int i = i0; i < (N4); i += stride) {                           \
            float4 v = ((const float4*)(SRC))[i];                           \
            ushort4 o;                                                      \
            o.x = f2bf(v.x); o.y = f2bf(v.y);                               \
            o.z = f2bf(v.z); o.w = f2bf(v.w);                               \
            ((ushort4*)(DST))[(DOFF) + i] = o;                              \
        }
    CVT4(x, x_bf, (TB * IN_) / 4, 0)
    CVT4(Wihf, wih_cat, (G4 * IN_) / 4, 0)
    CVT4(Wihb, wih_cat, (G4 * IN_) / 4, (G4 * IN_) / 4)
    CVT4(Whhf, whhf_bf, (G4 * HH) / 4, 0)
    CVT4(Whhb, whhb_bf, (G4 * HH) / 4, 0)
    CVT4(Wlin, wlin_bf, (OUTD * 2 * HH) / 4, 0)
    #undef CVT4
    for (int i = i0; i < G4; i += stride) {
        bias_cat[i]      = bihf[i] + bhhf[i];
        bias_cat[G4 + i] = bihb[i] + bhhb[i];
    }
    for (int i = i0; i < 131072; i += stride)  // 2 MB: slow + fast exchange tags -> 0
        exch[i] = uint4{0u, 0u, 0u, 0u};
}

// ---- 128x128-tile bf16 MFMA GEMM: C[M,N] = A[M,K] * W[N,K]^T + bias[N] ----
// gll16 staging into LINEAR LDS + both-sides XOR swizzle (r9, verified ~+70us).
__global__ __launch_bounds__(256) void gemm_bias_kernel(
    const u16* __restrict__ A, const u16* __restrict__ W,
    const float* __restrict__ bias, void* __restrict__ Cout,
    int M, int N, int K, int out_is_bf16) {
    __shared__ __align__(16) u16 lA[128 * 64];
    __shared__ __align__(16) u16 lB[128 * 64];
    const int tid = threadIdx.x;
    const int m0 = blockIdx.x * 128;
    const int n0 = blockIdx.y * 128;
    const int wave = tid >> 6, lane = tid & 63;
    const int wm = wave >> 1, wn = wave & 1;
    const int lrow = lane & 15, lq = lane >> 4;
    const int srow = lane >> 3;
    const int ssw  = (lane & 7) ^ srow;

    f32x4 acc[4][4] = {};

    for (int kc = 0; kc < K; kc += 64) {
        #pragma unroll
        for (int i = 0; i < 4; ++i) {
            int chunk = wave + i * 4;
            int row = chunk * 8 + srow;
            gll16(&A[(size_t)(m0 + row) * K + kc + ssw * 8], &lA[chunk * 512]);
            gll16(&W[(size_t)(n0 + row) * K + kc + ssw * 8], &lB[chunk * 512]);
        }
        __syncthreads();
        #pragma unroll
        for (int ks = 0; ks < 2; ++ks) {
            bf16x8 af[4], bfr[4];
            #pragma unroll
            for (int mf = 0; mf < 4; ++mf) {
                int row = wm * 64 + mf * 16 + lrow;
                int c16 = (ks * 4 + lq) ^ (row & 7);
                af[mf] = *(const bf16x8*)(&lA[row * 64 + c16 * 8]);
            }
            #pragma unroll
            for (int nf = 0; nf < 4; ++nf) {
                int row = wn * 64 + nf * 16 + lrow;
                int c16 = (ks * 4 + lq) ^ (row & 7);
                bfr[nf] = *(const bf16x8*)(&lB[row * 64 + c16 * 8]);
            }
            #pragma unroll
            for (int mf = 0; mf < 4; ++mf)
                #pragma unroll
                for (int nf = 0; nf < 4; ++nf)
                    acc[mf][nf] = MFMA16(af[mf], bfr[nf], acc[mf][nf]);
        }
        __syncthreads();
    }

    #pragma unroll
    for (int mf = 0; mf < 4; ++mf) {
        #pragma unroll
        for (int nf = 0; nf < 4; ++nf) {
            int row = m0 + wm * 64 + mf * 16 + lq * 4;
            int col = n0 + wn * 64 + nf * 16 + lrow;
            float bv = bias[col];
            f32x4 v = acc[mf][nf];
            #pragma unroll
            for (int r = 0; r < 4; ++r) {
                float val = v[r] + bv;
                if (out_is_bf16)
                    ((u16*)Cout)[(size_t)(row + r) * N + col] = f2bf(val);
                else
                    ((float*)Cout)[(size_t)(row + r) * N + col] = val;
            }
        }
    }
}

// ---- persistent fused recurrence, hybrid L2-fast / L3-correct handoff ----
// grid = 256 blocks; XCD-co-located groups (slot=bx&7; r8 evidence: 5x FETCH
// drop => group members share one L2). Producer dual-publishes each tagged
// u64: workgroup-scope atomic (plain cached, write-through vL1 -> own L2) to
// exchf, PLUS relaxed agent-scope (UC, L3) to exch. Consumer retry loop is
// DEADLOCK-FREE BY CONSTRUCTION: each iteration tries <=8 fast sc0 volleys
// (L2-served when co-located), then ONE slow UC volley -- the guaranteed
// channel is consulted every iteration, so any wrong mapping assumption costs
// bounded time, never liveness. Tags make staleness a retry, never corruption.
__global__ __launch_bounds__(256, 1) void lstm_persist_kernel(
    const u16* __restrict__ xw, const u16* __restrict__ whh_f,
    const u16* __restrict__ whh_b, u16* __restrict__ hcat,
    u64* __restrict__ exch, u64* __restrict__ exchf) {
    const int bx = blockIdx.x;
    const int slot = bx & 7;                 // XCD slot (round-robin dispatch)
    const int jt  = (bx >> 3) & 15;
    const int g   = slot + 8 * (bx >> 7);    // group 0..15
    const int dir = g >> 3;
    const int bt  = g & 7;
    const u16* __restrict__ whh = dir ? whh_b : whh_f;
    const int b0 = bt * 16;
    const int j0 = jt * 32;

    __shared__ __align__(16) u16 lh[16 * 520];
    __shared__ float sgate[4][16][33];

    const int tid = threadIdx.x;
    const int wave = tid >> 6, lane = tid & 63;
    const int lrow = lane & 15, lq = lane >> 4;

    // ---- preload this wave's W_hh slice (gate `wave`, 32 rows x K=512) ----
    const u16* wrow = whh + ((size_t)wave * HH + j0) * HH;
    bf16x8 w0[16], w1[16];
    #pragma unroll
    for (int kc = 0; kc < 16; ++kc) {
        w0[kc] = *(const bf16x8*)(&wrow[(size_t)lrow * HH + kc * 32 + lq * 8]);
        w1[kc] = *(const bf16x8*)(&wrow[(size_t)(16 + lrow) * HH + kc * 32 + lq * 8]);
    }
    #pragma unroll
    for (int kc = 0; kc < 16; ++kc)
        asm volatile("" : "+v"(w0[kc]), "+v"(w1[kc]));

    const int bl = tid >> 4;
    const int jj = (tid & 15) * 2;
    float cr0 = 0.f, cr1 = 0.f;

    const size_t my_ex = ((size_t)dir * BB + b0 + bl) * 256 + (j0 >> 1) + (tid & 15);

    for (int s = 0; s < TT; ++s) {
        const int t = dir ? (TT - 1 - s) : s;

        // prefetch xw for this thread's 2 cells (4 gates, u32 each)
        const u16* xrow = xw + ((size_t)t * BB + b0 + bl) * (2 * G4) + dir * G4 + j0 + jj;
        unsigned xg[4];
        #pragma unroll
        for (int gg = 0; gg < 4; ++gg)
            xg[gg] = *(const unsigned*)(xrow + (size_t)gg * HH);

        f32x4 acc0 = {}, acc1 = {}, acc0b = {}, acc1b = {};
        if (s > 0) {
            const int p = (s - 1) & 1;
            const size_t ebase = ((size_t)(p * 2 + dir) * BB + b0) * 256 + tid;
            const u64* exs = exch  + ebase;
            const u64* exf = exchf + ebase;
            const u64 expect = ((u64)(unsigned)s << 48) | ((u64)(unsigned)s << 16);
            u64 v[16];
            for (;;) {
                bool got = false;
                #pragma unroll 1
                for (int it = 0; it < 8 && !got; ++it) {
                    fast_volley16(exf, v);          // L2 path (when co-located)
                    got = tag_ok(v, expect);
                }
                if (got) break;
                slow_volley16(exs, v);              // guaranteed UC/L3 channel
                if (tag_ok(v, expect)) break;
            }

            // unpack to lh: cells (2*tid, 2*tid+1) of row i -> packed u32
            #pragma unroll
            for (int i = 0; i < 16; ++i)
                *(unsigned*)(&lh[i * 520 + tid * 2]) =
                    (unsigned)(v[i] & 0xffffu) | (unsigned)((v[i] >> 16) & 0xffff0000u);
            __syncthreads();   // bar A: lh ready

            #pragma unroll
            for (int kc = 0; kc < 16; kc += 2) {
                bf16x8 a0 = *(const bf16x8*)(&lh[lrow * 520 + kc * 32 + lq * 8]);
                bf16x8 a1 = *(const bf16x8*)(&lh[lrow * 520 + (kc + 1) * 32 + lq * 8]);
                acc0  = MFMA16(a0, w0[kc], acc0);
                acc1  = MFMA16(a0, w1[kc], acc1);
                acc0b = MFMA16(a1, w0[kc + 1], acc0b);
                acc1b = MFMA16(a1, w1[kc + 1], acc1b);
            }
            acc0 += acc0b;
            acc1 += acc1b;
        }

        // gates -> LDS (D layout: m = lq*4+r batch-local, n in {lrow, 16+lrow})
        #pragma unroll
        for (int r = 0; r < 4; ++r) {
            sgate[wave][lq * 4 + r][lrow]      = acc0[r];
            sgate[wave][lq * 4 + r][16 + lrow] = acc1[r];
        }
        __syncthreads();   // bar B: gates ready (also protects lh vs next fill)

        // pointwise: 2 adjacent cells per thread, c in registers
        float gi0 = sgate[0][bl][jj]     + bf2f((u16)(xg[0] & 0xffffu));
        float gf0 = sgate[1][bl][jj]     + bf2f((u16)(xg[1] & 0xffffu));
        float gg0 = sgate[2][bl][jj]     + bf2f((u16)(xg[2] & 0xffffu));
        float go0 = sgate[3][bl][jj]     + bf2f((u16)(xg[3] & 0xffffu));
        float gi1 = sgate[0][bl][jj + 1] + bf2f((u16)(xg[0] >> 16));
        float gf1 = sgate[1][bl][jj + 1] + bf2f((u16)(xg[1] >> 16));
        float gg1 = sgate[2][bl][jj + 1] + bf2f((u16)(xg[2] >> 16));
        float go1 = sgate[3][bl][jj + 1] + bf2f((u16)(xg[3] >> 16));

        float c0 = sigmoid_f(gf0) * cr0 + sigmoid_f(gi0) * tanh_f(gg0);
        float c1 = sigmoid_f(gf1) * cr1 + sigmoid_f(gi1) * tanh_f(gg1);
        cr0 = c0; cr1 = c1;
        float h0 = sigmoid_f(go0) * tanh_f(c0);
        float h1 = sigmoid_f(go1) * tanh_f(c1);

        // dual publish: fast cached (workgroup-scope atomic -> own L2), then
        // slow UC (agent scope -> L3, correctness channel), then hcat.
        unsigned hb0 = (unsigned)f2bf(h0), hb1 = (unsigned)f2bf(h1);
        unsigned tagv = (unsigned)(s + 1) << 16;
        u64 pv = (u64)(tagv | hb0) | ((u64)(tagv | hb1) << 32);
        const size_t pub = (size_t)((s & 1) * 2) * BB * 256 + my_ex;
        __hip_atomic_store(exchf + pub, pv, __ATOMIC_RELAXED,
                           __HIP_MEMORY_SCOPE_WORKGROUP);
        __hip_atomic_store(exch + pub, pv, __ATOMIC_RELAXED,
                           __HIP_MEMORY_SCOPE_AGENT);

        *(unsigned*)(hcat + ((size_t)t * BB + b0 + bl) * (2 * HH) + dir * HH + j0 + jj) =
            hb0 | (hb1 << 16);
    }
}

// ---- workspace layout (bytes) ----
#define OFF_XBF    ((size_t)0)                             // 16,777,216
#define OFF_WIH    (OFF_XBF  + (size_t)TB * IN_ * 2)       // stacked W_ih: 4,194,304
#define OFF_WHHF   (OFF_WIH  + (size_t)2 * G4 * IN_ * 2)
#define OFF_WHHB   (OFF_WHHF + (size_t)G4 * HH * 2)
#define OFF_WLIN   (OFF_WHHB + (size_t)G4 * HH * 2)
#define OFF_BIAS   (OFF_WLIN + (size_t)OUTD * 2 * HH * 2)  // stacked bias: 16,384
#define OFF_XW     (OFF_BIAS + (size_t)2 * G4 * 4)         // [TB][4096]: 134,217,728
#define OFF_HCAT   (OFF_XW   + (size_t)TB * 2 * G4 * 2)    // 33,554,432
#define OFF_EXCH   (OFF_HCAT + (size_t)TB * 2 * HH * 2)    // slow UC exchange: 1 MB
#define OFF_EXCHF  (OFF_EXCH + (size_t)2 * 2 * BB * HH * 4) // fast L2 exchange: 1 MB
#define WS_NEED    (OFF_EXCHF + (size_t)2 * 2 * BB * HH * 4)

extern "C" void kernel_launch(void* const* d_in, const int* in_sizes, int n_in,
                              void* d_out, int out_size, void* d_ws, size_t ws_size,
                              hipStream_t stream) {
    (void)in_sizes; (void)n_in; (void)out_size;
    if (ws_size < WS_NEED) return;

    const float* x    = (const float*)d_in[0];
    const float* Wihf = (const float*)d_in[1];
    const float* Whhf = (const float*)d_in[2];
    const float* bihf = (const float*)d_in[3];
    const float* bhhf = (const float*)d_in[4];
    const float* Wihb = (const float*)d_in[5];
    const float* Whhb = (const float*)d_in[6];
    const float* bihb = (const float*)d_in[7];
    const float* bhhb = (const float*)d_in[8];
    const float* Wlin = (const float*)d_in[9];
    const float* blin = (const float*)d_in[10];
    float* out = (float*)d_out;

    char* ws = (char*)d_ws;
    u16* x_bf     = (u16*)(ws + OFF_XBF);
    u16* wih_cat  = (u16*)(ws + OFF_WIH);
    u16* whhf_bf  = (u16*)(ws + OFF_WHHF);
    u16* whhb_bf  = (u16*)(ws + OFF_WHHB);
    u16* wlin_bf  = (u16*)(ws + OFF_WLIN);
    float* bias_cat = (float*)(ws + OFF_BIAS);
    u16* xw    = (u16*)(ws + OFF_XW);
    u16* hcat  = (u16*)(ws + OFF_HCAT);
    u64* exch  = (u64*)(ws + OFF_EXCH);
    u64* exchf = (u64*)(ws + OFF_EXCHF);

    // prep: all converts + stacked bias + both exchange buffers zeroed
    prep_kernel<<<1024, 256, 0, stream>>>(x, Wihf, Wihb, Whhf, Whhb, Wlin,
                                          bihf, bhhf, bihb, bhhb,
                                          x_bf, wih_cat, whhf_bf, whhb_bf, wlin_bf,
                                          bias_cat, (uint4*)exch);

    // phase 1: xw = x @ [W_ih_f; W_ih_b]^T + bias_cat, bf16 out, ONE GEMM (N=4096)
    gemm_bias_kernel<<<dim3(TB / 128, (2 * G4) / 128), 256, 0, stream>>>(
        x_bf, wih_cat, bias_cat, xw, TB, 2 * G4, IN_, 1);

    // phase 2: persistent kernel, all 128 recurrent steps, both dirs.
    lstm_persist_kernel<<<256, 256, 0, stream>>>(xw, whhf_bf, whhb_bf, hcat,
                                                 exch, exchf);

    // phase 3: out = hcat @ W_lin^T + b_lin, fp32 out
    gemm_bias_kernel<<<dim3(TB / 128, OUTD / 128), 256, 0, stream>>>(
        hcat, wlin_bf, blin, out, TB, OUTD, 2 * HH, 0);
}